// Round 5
// baseline (358.116 us; speedup 1.0000x reference)
//
#include <hip/hip_runtime.h>
#include <hip/hip_bf16.h>
#include <math.h>

#define B_ 2
#define L_ 1024
#define H_ 1024
#define D_ 2048
#define N_ 16
#define R_ 64
#define DPB 4      // d's per scan block
#define NCK 64     // chunks per sequence
#define CL 16      // chunk length (NCK*CL == L_)

typedef short short8 __attribute__((ext_vector_type(8)));
typedef float floatx4 __attribute__((ext_vector_type(4)));

__device__ __forceinline__ float siluf(float g) {
    return g / (1.0f + __expf(-g));
}

__device__ __forceinline__ unsigned short f2bf(float f) {
    unsigned int u = __float_as_uint(f);
    u = (u + 0x7fffu + ((u >> 16) & 1u)) >> 16;  // RNE
    return (unsigned short)u;
}

// async global->LDS, 16B per lane; lds base must be wave-uniform
__device__ __forceinline__ void gl2lds(const unsigned short* g, unsigned short* l) {
    __builtin_amdgcn_global_load_lds(
        (const __attribute__((address_space(1))) unsigned int*)g,
        (__attribute__((address_space(3))) unsigned int*)l, 16, 0, 0);
}

// ---------------- fp32 -> bf16 convert (vectorized) ----------------
__global__ __launch_bounds__(256) void cvt_bf16(
    const float* __restrict__ in, unsigned short* __restrict__ out, int n)
{
    int i = (blockIdx.x * 256 + threadIdx.x) * 4;
    if (i >= n) return;
    float4 v = *(const float4*)(in + i);
    ushort4 o;
    o.x = f2bf(v.x); o.y = f2bf(v.y); o.z = f2bf(v.z); o.w = f2bf(v.w);
    *(ushort4*)(out + i) = o;
}

// strided convert: ssm_p[m][96] cols 0..63 -> packed bf16 [m][64]
__global__ __launch_bounds__(256) void cvt_sp64(
    const float* __restrict__ in, unsigned short* __restrict__ out)
{
    int i = blockIdx.x * 256 + threadIdx.x;   // 2048*16 quads
    int m = i >> 4;
    int r = (i & 15) * 4;
    float4 v = *(const float4*)(in + (size_t)m * 96 + r);
    ushort4 o;
    o.x = f2bf(v.x); o.y = f2bf(v.y); o.z = f2bf(v.z); o.w = f2bf(v.w);
    *(ushort4*)(out + (size_t)m * 64 + r) = o;
}

// ---------------- bf16 MFMA GEMM: C = A[M,K] @ B[N,K]^T ----------------
// 128x128 tile, BK=32, 256 threads (4 waves, 2x2 of 64x64), 16x16x32 MFMA,
// global_load_lds width-16 staging. Row strides of A and B must equal K.
// EPI: 0 = plain store C[m][n], 1 = atomicAdd C[m][n] (K-split),
//      2 = transposed float4 store C[n][m], 3 = softplus(acc + bias[m-row]) store C[m][n]
template<int EPI>
__global__ __launch_bounds__(256) void gemm_bf16_nt(
    const unsigned short* __restrict__ A, const unsigned short* __restrict__ Bm,
    float* __restrict__ C, int K, int Ncols, int ldc, int kChunk, int nMax,
    const float* __restrict__ bias)
{
    __shared__ unsigned short As[128 * 32];
    __shared__ unsigned short Bs[128 * 32];
    const int tid  = threadIdx.x;
    const int lane = tid & 63;
    const int wave = tid >> 6;
    const int wm = (wave >> 1) * 64;
    const int wn = (wave & 1) * 64;
    const int lr   = lane & 15;
    const int quad = lane >> 4;
    const int m0 = blockIdx.y * 128;
    const int n0 = blockIdx.x * 128;
    const int k0 = blockIdx.z * kChunk;

    const int srow = wave * 32 + (lane >> 2);
    const int sq   = (lane & 3) * 8;
    unsigned short* AsB0 = &As[(wave * 32) * 32];
    unsigned short* AsB1 = &As[(wave * 32 + 16) * 32];
    unsigned short* BsB0 = &Bs[(wave * 32) * 32];
    unsigned short* BsB1 = &Bs[(wave * 32 + 16) * 32];
    const size_t aoff0 = (size_t)(m0 + srow) * K + sq;
    const size_t aoff1 = (size_t)(m0 + srow + 16) * K + sq;
    const size_t boff0 = (size_t)min(n0 + srow, nMax - 1) * K + sq;
    const size_t boff1 = (size_t)min(n0 + srow + 16, nMax - 1) * K + sq;

    floatx4 acc[4][4];
#pragma unroll
    for (int mi = 0; mi < 4; ++mi)
#pragma unroll
        for (int ni = 0; ni < 4; ++ni)
            acc[mi][ni] = (floatx4){0.f, 0.f, 0.f, 0.f};

    for (int kt = k0; kt < k0 + kChunk; kt += 32) {
        __syncthreads();
        gl2lds(A + aoff0 + kt, AsB0);
        gl2lds(A + aoff1 + kt, AsB1);
        gl2lds(Bm + boff0 + kt, BsB0);
        gl2lds(Bm + boff1 + kt, BsB1);
        __syncthreads();
        short8 af[4], bf[4];
#pragma unroll
        for (int mi = 0; mi < 4; ++mi)
            af[mi] = *(const short8*)&As[(wm + mi * 16 + lr) * 32 + quad * 8];
#pragma unroll
        for (int ni = 0; ni < 4; ++ni)
            bf[ni] = *(const short8*)&Bs[(wn + ni * 16 + lr) * 32 + quad * 8];
#pragma unroll
        for (int mi = 0; mi < 4; ++mi)
#pragma unroll
            for (int ni = 0; ni < 4; ++ni)
                acc[mi][ni] = __builtin_amdgcn_mfma_f32_16x16x32_bf16(
                    af[mi], bf[ni], acc[mi][ni], 0, 0, 0);
    }

#pragma unroll
    for (int mi = 0; mi < 4; ++mi)
#pragma unroll
        for (int ni = 0; ni < 4; ++ni) {
            const int rr = m0 + wm + mi * 16 + quad * 4;
            const int cc = n0 + wn + ni * 16 + lr;
            if (cc >= Ncols) continue;
            if (EPI == 2) {
                float4 v = make_float4(acc[mi][ni][0], acc[mi][ni][1],
                                       acc[mi][ni][2], acc[mi][ni][3]);
                *(float4*)&C[(size_t)cc * ldc + rr] = v;
            } else {
#pragma unroll
                for (int r = 0; r < 4; ++r) {
                    if (EPI == 0) {
                        C[(size_t)(rr + r) * ldc + cc] = acc[mi][ni][r];
                    } else if (EPI == 1) {
                        atomicAdd(&C[(size_t)(rr + r) * ldc + cc], acc[mi][ni][r]);
                    } else {
                        float z = acc[mi][ni][r] + bias[rr + r];
                        float spv = (z > 0.f) ? (z + log1pf(__expf(-z)))
                                              : log1pf(__expf(z));
                        C[(size_t)(rr + r) * ldc + cc] = spv;
                    }
                }
            }
        }
}

// ---------------- causal depthwise conv (K=4) + bias + SiLU, d-major ----------------
__global__ __launch_bounds__(256) void conv_silu_kernel(
    const float* __restrict__ projT, const float* __restrict__ conv_w,
    const float* __restrict__ conv_b, float* __restrict__ xT,
    unsigned short* __restrict__ x_bf)
{
    __shared__ unsigned short tile[64][72];
    const int t = threadIdx.x;
    const int d0 = blockIdx.x * 64;
    const int lt0 = blockIdx.y * 64;
    const int b = blockIdx.z;
    const int dl = t & 63;
    const int seg = t >> 6;
    const int d = d0 + dl;
    const int l0 = lt0 + seg * 16;
    const float* row = projT + (size_t)d * 2048 + b * 1024;
    const float w0 = conv_w[d * 4 + 0], w1 = conv_w[d * 4 + 1];
    const float w2 = conv_w[d * 4 + 2], w3 = conv_w[d * 4 + 3];
    const float bias = conv_b[d];

    float p[19];
    p[0] = (l0 >= 3) ? row[l0 - 3] : 0.f;
    p[1] = (l0 >= 2) ? row[l0 - 2] : 0.f;
    p[2] = (l0 >= 1) ? row[l0 - 1] : 0.f;
#pragma unroll
    for (int j = 0; j < 16; j += 4) {
        float4 q = *(const float4*)(row + l0 + j);
        p[3 + j] = q.x; p[4 + j] = q.y; p[5 + j] = q.z; p[6 + j] = q.w;
    }
    float v[16];
#pragma unroll
    for (int j = 0; j < 16; ++j)
        v[j] = siluf(bias + w0 * p[j] + w1 * p[j + 1] + w2 * p[j + 2] + w3 * p[j + 3]);

    float* xrow = xT + (size_t)d * 2048 + b * 1024 + l0;
#pragma unroll
    for (int j = 0; j < 16; j += 4)
        *(float4*)(xrow + j) = make_float4(v[j], v[j + 1], v[j + 2], v[j + 3]);

#pragma unroll
    for (int j = 0; j < 16; ++j)
        tile[seg * 16 + j][dl] = f2bf(v[j]);
    __syncthreads();

    const int ml = t >> 2;
    const int c = t & 3;
    short8 s0 = *(const short8*)&tile[ml][c * 16];
    short8 s1 = *(const short8*)&tile[ml][c * 16 + 8];
    unsigned short* dst = x_bf + (size_t)(b * 1024 + lt0 + ml) * 2048 + d0 + c * 16;
    *(short8*)dst = s0;
    *(short8*)(dst + 8) = s1;
}

// ---------------- bf16 tiled transpose: yT[d][m] -> y[m][d] ----------------
__global__ __launch_bounds__(256) void transpose_bf16(
    const unsigned short* __restrict__ in, unsigned short* __restrict__ out)
{
    __shared__ unsigned short tile[64][72];
    const int t = threadIdx.x;
    const int d0 = blockIdx.x * 64;
    const int m0 = blockIdx.y * 64;
    {
        const int dl = t >> 2, c = t & 3;
        const unsigned short* src = in + (size_t)(d0 + dl) * 2048 + m0 + c * 16;
        *(short8*)&tile[dl][c * 16]     = *(const short8*)src;
        *(short8*)&tile[dl][c * 16 + 8] = *(const short8*)(src + 8);
    }
    __syncthreads();
    {
        const int ml = t >> 2, c = t & 3;
        unsigned short v[16];
#pragma unroll
        for (int j = 0; j < 16; ++j)
            v[j] = tile[c * 16 + j][ml];
        unsigned short* dst = out + (size_t)(m0 + ml) * 2048 + d0 + c * 16;
        *(short8*)dst = *(short8*)&v[0];
        *(short8*)(dst + 8) = *(short8*)&v[8];
    }
}

// ---------------- chunked selective scan, n-in-register (no shuffles) -----------
// thread <-> (d_local, chunk). h[16] in VGPRs; per-chunk P[n] = exp2(An2[n]*sum(dt)).
// Block: 256 thr = 4 d x 64 chunks of 16. Grid: (D/4, B) = 1024 blocks.
__global__ __launch_bounds__(256) void scan_kernel(
    const float* __restrict__ dtT, const float* __restrict__ xT,
    const float* __restrict__ projT, const float* __restrict__ sp,
    const float* __restrict__ A_log, const float* __restrict__ Dp,
    unsigned short* __restrict__ yT)
{
    __shared__ float Pc[DPB][NCK][16];   // becomes Hin in-place during combine
    __shared__ float Hc[DPB][NCK][16];

    const int tid = threadIdx.x;
    const int dl = tid >> 6;            // wave = one d_local
    const int ck = tid & 63;
    const int d = blockIdx.x * DPB + dl;
    const int b = blockIdx.y;
    const int mb = b * 1024 + ck * CL;

    // An2[n] = -exp(A_log[d][n]) * log2(e)  (exp2-ready)
    float An2[16];
    {
        const float* al = A_log + d * 16;
#pragma unroll
        for (int j = 0; j < 16; j += 4) {
            float4 a4 = *(const float4*)(al + j);
            An2[j + 0] = -__expf(a4.x) * 1.44269504f;
            An2[j + 1] = -__expf(a4.y) * 1.44269504f;
            An2[j + 2] = -__expf(a4.z) * 1.44269504f;
            An2[j + 3] = -__expf(a4.w) * 1.44269504f;
        }
    }

    const float* pdt = dtT + (size_t)d * 2048 + mb;
    const float* px  = xT + (size_t)d * 2048 + mb;
    const float* pg  = projT + (size_t)(2048 + d) * 2048 + mb;

    float h[16];
#pragma unroll
    for (int n = 0; n < 16; ++n) h[n] = 0.f;
    float dts = 0.f;

    // pass 1: chunk-local scan from zero
    for (int lq = 0; lq < CL; lq += 4) {
        float4 dt4 = *(const float4*)(pdt + lq);
        float4 x4  = *(const float4*)(px + lq);
        float dta[4] = {dt4.x, dt4.y, dt4.z, dt4.w};
        float xa[4]  = {x4.x, x4.y, x4.z, x4.w};
#pragma unroll
        for (int j = 0; j < 4; ++j) {
            const float* sprow = sp + (size_t)(mb + lq + j) * 96 + 64;
            float Bv[16];
#pragma unroll
            for (int q = 0; q < 16; q += 4) {
                float4 b4 = *(const float4*)(sprow + q);
                Bv[q] = b4.x; Bv[q + 1] = b4.y; Bv[q + 2] = b4.z; Bv[q + 3] = b4.w;
            }
            const float ub = dta[j] * xa[j];
            dts += dta[j];
#pragma unroll
            for (int n = 0; n < 16; ++n) {
                const float dA = __builtin_amdgcn_exp2f(dta[j] * An2[n]);
                h[n] = fmaf(dA, h[n], Bv[n] * ub);
            }
        }
    }
#pragma unroll
    for (int n = 0; n < 16; ++n) {
        Pc[dl][ck][n] = __builtin_amdgcn_exp2f(dts * An2[n]);
        Hc[dl][ck][n] = h[n];
    }
    __syncthreads();

    // combine: one thread per (d_local, n); Pc is overwritten with Hin in-place
    if (tid < DPB * 16) {
        const int dd = tid >> 4, nn = tid & 15;
        float hin = 0.f;
#pragma unroll 4
        for (int c = 0; c < NCK; ++c) {
            const float p = Pc[dd][c][nn];
            const float hcv = Hc[dd][c][nn];
            Pc[dd][c][nn] = hin;
            hin = fmaf(p, hin, hcv);
        }
    }
    __syncthreads();

#pragma unroll
    for (int n = 0; n < 16; ++n) h[n] = Pc[dl][ck][n];

    const float Dv = Dp[d];
    unsigned short* pyt = yT + (size_t)d * 2048 + mb;

    // pass 2: rescan with true h_in; in-register n-reduction; emit yT bf16
    for (int lq = 0; lq < CL; lq += 4) {
        float4 dt4 = *(const float4*)(pdt + lq);
        float4 x4  = *(const float4*)(px + lq);
        float4 g4  = *(const float4*)(pg + lq);
        float dta[4] = {dt4.x, dt4.y, dt4.z, dt4.w};
        float xa[4]  = {x4.x, x4.y, x4.z, x4.w};
        float ga[4]  = {g4.x, g4.y, g4.z, g4.w};
        ushort4 yv;
        unsigned short* yw = (unsigned short*)&yv;
#pragma unroll
        for (int j = 0; j < 4; ++j) {
            const float* sprow = sp + (size_t)(mb + lq + j) * 96 + 64;
            float Bv[16];
#pragma unroll
            for (int q = 0; q < 16; q += 4) {
                float4 b4 = *(const float4*)(sprow + q);
                Bv[q] = b4.x; Bv[q + 1] = b4.y; Bv[q + 2] = b4.z; Bv[q + 3] = b4.w;
            }
            const float ub = dta[j] * xa[j];
#pragma unroll
            for (int n = 0; n < 16; ++n) {
                const float dA = __builtin_amdgcn_exp2f(dta[j] * An2[n]);
                h[n] = fmaf(dA, h[n], Bv[n] * ub);
            }
            float Cv[16];
#pragma unroll
            for (int q = 0; q < 16; q += 4) {
                float4 c4 = *(const float4*)(sprow + 16 + q);
                Cv[q] = c4.x; Cv[q + 1] = c4.y; Cv[q + 2] = c4.z; Cv[q + 3] = c4.w;
            }
            float p = 0.f;
#pragma unroll
            for (int n = 0; n < 16; ++n)
                p = fmaf(h[n], Cv[n], p);
            yw[j] = f2bf(fmaf(xa[j], Dv, p) * siluf(ga[j]));
        }
        *(ushort4*)(pyt + lq) = yv;
    }
}

extern "C" void kernel_launch(void* const* d_in, const int* in_sizes, int n_in,
                              void* d_out, int out_size, void* d_ws, size_t ws_size,
                              hipStream_t stream)
{
    const float* hs     = (const float*)d_in[0];
    const float* W_in   = (const float*)d_in[1];
    const float* conv_w = (const float*)d_in[2];
    const float* conv_b = (const float*)d_in[3];
    const float* W_x    = (const float*)d_in[4];
    const float* W_dt   = (const float*)d_in[5];
    const float* b_dt   = (const float*)d_in[6];
    const float* A_log  = (const float*)d_in[7];
    const float* Dp     = (const float*)d_in[8];
    const float* W_out  = (const float*)d_in[9];
    float* out = (float*)d_out;

    // workspace (~74 MB), with overlays:
    float* ws    = (float*)d_ws;
    float* projT = ws;                               // [4096][2048] f32; rows 0..2047 become dtT
    float* xT    = projT + (size_t)4096 * 2048;      // [2048][2048] f32
    float* ssm_p = xT + (size_t)2048 * 2048;         // [2048][96] f32
    unsigned short* hs_bf    = (unsigned short*)(ssm_p + (size_t)2048 * 96);
    unsigned short* W_in_bf  = hs_bf + (size_t)2048 * 1024;      // 4096*1024
    unsigned short* W_out_bf = W_in_bf + (size_t)4096 * 1024;    // 1024*2048
    unsigned short* W_x_bf   = W_out_bf + (size_t)1024 * 2048;   // 96*2048
    unsigned short* x_bf     = W_x_bf + (size_t)96 * 2048;       // [2048 m][2048 d]
    unsigned short* W_dt_bf  = x_bf + (size_t)2048 * 2048;       // 2048*64
    unsigned short* sp64_bf  = W_dt_bf + (size_t)2048 * 64;      // 2048*64
    unsigned short* yT_bf    = hs_bf;                            // overlay (dead after proj GEMM)
    unsigned short* y_bf     = x_bf;                             // overlay (dead after ssm GEMM)
    float* dtT = projT;                                          // overlay rows 0..2047

    const int M = B_ * L_;  // 2048

    // 0. fp32 -> bf16 converts
    cvt_bf16<<<(2048 * 1024) / 1024, 256, 0, stream>>>(hs, hs_bf, 2048 * 1024);
    cvt_bf16<<<(4096 * 1024) / 1024, 256, 0, stream>>>(W_in, W_in_bf, 4096 * 1024);
    cvt_bf16<<<(1024 * 2048) / 1024, 256, 0, stream>>>(W_out, W_out_bf, 1024 * 2048);
    cvt_bf16<<<(96 * 2048) / 1024, 256, 0, stream>>>(W_x, W_x_bf, 96 * 2048);
    cvt_bf16<<<(2048 * 64) / 1024, 256, 0, stream>>>(W_dt, W_dt_bf, 2048 * 64);

    // 1. projT = (hs @ W_in^T)^T : [4096 e][2048 m] (bf16 MFMA, transposed store)
    gemm_bf16_nt<2><<<dim3(4096 / 128, M / 128, 1), 256, 0, stream>>>(
        hs_bf, W_in_bf, projT, 1024, 4096, 2048, 1024, 4096, nullptr);

    // 2. conv + SiLU: projT rows 0..2047 -> xT[d][m] fp32 + x_bf[m][d] bf16
    conv_silu_kernel<<<dim3(D_ / 64, L_ / 64, B_), 256, 0, stream>>>(
        projT, conv_w, conv_b, xT, x_bf);

    // 3. ssm_p[m][96] = x @ W_x^T, K=2048 split 8 (bf16 MFMA, atomic fp32)
    hipMemsetAsync(ssm_p, 0, (size_t)M * 96 * sizeof(float), stream);
    gemm_bf16_nt<1><<<dim3(1, M / 128, 8), 256, 0, stream>>>(
        x_bf, W_x_bf, ssm_p, 2048, 96, 96, 256, 96, nullptr);

    // 3b. pack dt_lr cols 0..63 -> bf16 [m][64]
    cvt_sp64<<<(2048 * 16) / 256, 256, 0, stream>>>(ssm_p, sp64_bf);

    // 4. dtT[d][m] = softplus(W_dt @ dt_lr^T + b_dt[d]) (bf16 MFMA, EPI=3)
    gemm_bf16_nt<3><<<dim3(M / 128, 2048 / 128, 1), 256, 0, stream>>>(
        W_dt_bf, sp64_bf, dtT, 64, 2048, 2048, 64, 2048, b_dt);

    // 5. chunked scan (n-in-register) + fused gating -> yT[d][m] bf16
    scan_kernel<<<dim3(D_ / DPB, B_), 256, 0, stream>>>(
        dtT, xT, projT, ssm_p, A_log, Dp, yT_bf);

    // 6. transpose yT -> y[m][d] bf16
    transpose_bf16<<<dim3(2048 / 64, 2048 / 64), 256, 0, stream>>>(yT_bf, y_bf);

    // 7. out = y @ W_out^T : [2048,1024], K=2048 split 2 (bf16 MFMA, atomic fp32)
    hipMemsetAsync(out, 0, (size_t)M * 1024 * sizeof(float), stream);
    gemm_bf16_nt<1><<<dim3(1024 / 128, M / 128, 2), 256, 0, stream>>>(
        y_bf, W_out_bf, out, 2048, 1024, 1024, 1024, 1024, nullptr);
}

// Round 6
// 297.536 us; speedup vs baseline: 1.2036x; 1.2036x over previous
//
#include <hip/hip_runtime.h>
#include <hip/hip_bf16.h>
#include <math.h>

#define B_ 2
#define L_ 1024
#define H_ 1024
#define D_ 2048
#define N_ 16
#define R_ 64
#define NCK 32     // chunks per sequence
#define CL 32      // chunk length (NCK*CL == L_)

typedef short short8 __attribute__((ext_vector_type(8)));
typedef float floatx4 __attribute__((ext_vector_type(4)));

__device__ __forceinline__ float siluf(float g) {
    return g / (1.0f + __expf(-g));
}

__device__ __forceinline__ unsigned short f2bf(float f) {
    unsigned int u = __float_as_uint(f);
    u = (u + 0x7fffu + ((u >> 16) & 1u)) >> 16;  // RNE
    return (unsigned short)u;
}

__device__ __forceinline__ float bf2f(unsigned short u) {
    return __uint_as_float(((unsigned int)u) << 16);
}

// async global->LDS, 16B per lane; lds base must be wave-uniform
__device__ __forceinline__ void gl2lds(const unsigned short* g, unsigned short* l) {
    __builtin_amdgcn_global_load_lds(
        (const __attribute__((address_space(1))) unsigned int*)g,
        (__attribute__((address_space(3))) unsigned int*)l, 16, 0, 0);
}

// ---------------- fp32 -> bf16 convert (vectorized) ----------------
__global__ __launch_bounds__(256) void cvt_bf16(
    const float* __restrict__ in, unsigned short* __restrict__ out, int n)
{
    int i = (blockIdx.x * 256 + threadIdx.x) * 4;
    if (i >= n) return;
    float4 v = *(const float4*)(in + i);
    ushort4 o;
    o.x = f2bf(v.x); o.y = f2bf(v.y); o.z = f2bf(v.z); o.w = f2bf(v.w);
    *(ushort4*)(out + i) = o;
}

// strided convert: ssm_p[m][96] cols 0..63 -> packed bf16 [m][64]
__global__ __launch_bounds__(256) void cvt_sp64(
    const float* __restrict__ in, unsigned short* __restrict__ out)
{
    int i = blockIdx.x * 256 + threadIdx.x;   // 2048*16 quads
    int m = i >> 4;
    int r = (i & 15) * 4;
    float4 v = *(const float4*)(in + (size_t)m * 96 + r);
    ushort4 o;
    o.x = f2bf(v.x); o.y = f2bf(v.y); o.z = f2bf(v.z); o.w = f2bf(v.w);
    *(ushort4*)(out + (size_t)m * 64 + r) = o;
}

// ---------------- bf16 MFMA GEMM: C = A[M,K] @ B[N,K]^T ----------------
// 128x128 tile, BK=32, 256 threads (4 waves, 2x2 of 64x64), 16x16x32 MFMA,
// global_load_lds width-16 staging. Row strides of A and B must equal K.
// EPI: 0 = plain store C[m][n], 1 = atomicAdd C[m][n] (K-split),
//      3 = softplus(acc + bias[col]) store C[m][n],
//      4 = proj hybrid: n<2048 -> transposed float4 store C[n][m] (d-major);
//                       n>=2048 -> C2[m][n-2048] m-major store (gate)
template<int EPI>
__global__ __launch_bounds__(256) void gemm_bf16_nt(
    const unsigned short* __restrict__ A, const unsigned short* __restrict__ Bm,
    float* __restrict__ C, int K, int Ncols, int ldc, int kChunk, int nMax,
    const float* __restrict__ bias, float* __restrict__ C2)
{
    __shared__ unsigned short As[128 * 32];
    __shared__ unsigned short Bs[128 * 32];
    const int tid  = threadIdx.x;
    const int lane = tid & 63;
    const int wave = tid >> 6;
    const int wm = (wave >> 1) * 64;
    const int wn = (wave & 1) * 64;
    const int lr   = lane & 15;
    const int quad = lane >> 4;
    const int m0 = blockIdx.y * 128;
    const int n0 = blockIdx.x * 128;
    const int k0 = blockIdx.z * kChunk;

    const int srow = wave * 32 + (lane >> 2);
    const int sq   = (lane & 3) * 8;
    unsigned short* AsB0 = &As[(wave * 32) * 32];
    unsigned short* AsB1 = &As[(wave * 32 + 16) * 32];
    unsigned short* BsB0 = &Bs[(wave * 32) * 32];
    unsigned short* BsB1 = &Bs[(wave * 32 + 16) * 32];
    const size_t aoff0 = (size_t)(m0 + srow) * K + sq;
    const size_t aoff1 = (size_t)(m0 + srow + 16) * K + sq;
    const size_t boff0 = (size_t)min(n0 + srow, nMax - 1) * K + sq;
    const size_t boff1 = (size_t)min(n0 + srow + 16, nMax - 1) * K + sq;

    floatx4 acc[4][4];
#pragma unroll
    for (int mi = 0; mi < 4; ++mi)
#pragma unroll
        for (int ni = 0; ni < 4; ++ni)
            acc[mi][ni] = (floatx4){0.f, 0.f, 0.f, 0.f};

    for (int kt = k0; kt < k0 + kChunk; kt += 32) {
        __syncthreads();
        gl2lds(A + aoff0 + kt, AsB0);
        gl2lds(A + aoff1 + kt, AsB1);
        gl2lds(Bm + boff0 + kt, BsB0);
        gl2lds(Bm + boff1 + kt, BsB1);
        __syncthreads();
        short8 af[4], bf[4];
#pragma unroll
        for (int mi = 0; mi < 4; ++mi)
            af[mi] = *(const short8*)&As[(wm + mi * 16 + lr) * 32 + quad * 8];
#pragma unroll
        for (int ni = 0; ni < 4; ++ni)
            bf[ni] = *(const short8*)&Bs[(wn + ni * 16 + lr) * 32 + quad * 8];
#pragma unroll
        for (int mi = 0; mi < 4; ++mi)
#pragma unroll
            for (int ni = 0; ni < 4; ++ni)
                acc[mi][ni] = __builtin_amdgcn_mfma_f32_16x16x32_bf16(
                    af[mi], bf[ni], acc[mi][ni], 0, 0, 0);
    }

#pragma unroll
    for (int mi = 0; mi < 4; ++mi)
#pragma unroll
        for (int ni = 0; ni < 4; ++ni) {
            const int rr = m0 + wm + mi * 16 + quad * 4;
            const int cc = n0 + wn + ni * 16 + lr;
            if (cc >= Ncols) continue;
            if (EPI == 4) {
                if (n0 < 2048) {
                    float4 v = make_float4(acc[mi][ni][0], acc[mi][ni][1],
                                           acc[mi][ni][2], acc[mi][ni][3]);
                    *(float4*)&C[(size_t)cc * ldc + rr] = v;
                } else {
#pragma unroll
                    for (int r = 0; r < 4; ++r)
                        C2[(size_t)(rr + r) * 2048 + (cc - 2048)] = acc[mi][ni][r];
                }
            } else {
#pragma unroll
                for (int r = 0; r < 4; ++r) {
                    if (EPI == 0) {
                        C[(size_t)(rr + r) * ldc + cc] = acc[mi][ni][r];
                    } else if (EPI == 1) {
                        atomicAdd(&C[(size_t)(rr + r) * ldc + cc], acc[mi][ni][r]);
                    } else {
                        float z = acc[mi][ni][r] + bias[cc];
                        float spv = (z > 0.f) ? (z + log1pf(__expf(-z)))
                                              : log1pf(__expf(z));
                        C[(size_t)(rr + r) * ldc + cc] = spv;
                    }
                }
            }
        }
}

// ---------------- causal depthwise conv (K=4) + bias + SiLU, d-major in ----------------
// reads projx[d][m] rows (contiguous), writes x_bf[m][d] bf16 (LDS transpose)
__global__ __launch_bounds__(256) void conv_silu_kernel(
    const float* __restrict__ projx, const float* __restrict__ conv_w,
    const float* __restrict__ conv_b, unsigned short* __restrict__ x_bf)
{
    __shared__ unsigned short tile[64][72];
    const int t = threadIdx.x;
    const int d0 = blockIdx.x * 64;
    const int lt0 = blockIdx.y * 64;
    const int b = blockIdx.z;
    const int dl = t & 63;
    const int seg = t >> 6;
    const int d = d0 + dl;
    const int l0 = lt0 + seg * 16;
    const float* row = projx + (size_t)d * 2048 + b * 1024;
    const float w0 = conv_w[d * 4 + 0], w1 = conv_w[d * 4 + 1];
    const float w2 = conv_w[d * 4 + 2], w3 = conv_w[d * 4 + 3];
    const float bias = conv_b[d];

    float p[19];
    p[0] = (l0 >= 3) ? row[l0 - 3] : 0.f;
    p[1] = (l0 >= 2) ? row[l0 - 2] : 0.f;
    p[2] = (l0 >= 1) ? row[l0 - 1] : 0.f;
#pragma unroll
    for (int j = 0; j < 16; j += 4) {
        float4 q = *(const float4*)(row + l0 + j);
        p[3 + j] = q.x; p[4 + j] = q.y; p[5 + j] = q.z; p[6 + j] = q.w;
    }
#pragma unroll
    for (int j = 0; j < 16; ++j) {
        float v = siluf(bias + w0 * p[j] + w1 * p[j + 1] + w2 * p[j + 2] + w3 * p[j + 3]);
        tile[seg * 16 + j][dl] = f2bf(v);
    }
    __syncthreads();

    const int ml = t >> 2;
    const int c = t & 3;
    short8 s0 = *(const short8*)&tile[ml][c * 16];
    short8 s1 = *(const short8*)&tile[ml][c * 16 + 8];
    unsigned short* dst = x_bf + (size_t)(b * 1024 + lt0 + ml) * 2048 + d0 + c * 16;
    *(short8*)dst = s0;
    *(short8*)(dst + 8) = s1;
}

// ---------------- scan pass 1: per-chunk P[n], H[n] (from h=0) ----------------
// block = 256 consecutive d; grid (D/256, NCK, B). All global ops lane-coalesced.
// B-values staged in LDS (broadcast reads).
__global__ __launch_bounds__(256) void scan_p1(
    const float* __restrict__ dt, const unsigned short* __restrict__ x_bf,
    const float* __restrict__ sp, const float* __restrict__ A_log,
    float* __restrict__ Pch, float* __restrict__ Hch)
{
    __shared__ float sB[CL][16];
    const int tid = threadIdx.x;
    const int d = blockIdx.x * 256 + tid;
    const int ck = blockIdx.y;
    const int b = blockIdx.z;
    const int mb = b * 1024 + ck * CL;

    if (tid < CL * 4) {
        int row = tid >> 2, q = (tid & 3) * 4;
        *(float4*)&sB[row][q] = *(const float4*)(sp + (size_t)(mb + row) * 96 + 64 + q);
    }
    float An2[16];
    {
        const float* al = A_log + d * 16;
#pragma unroll
        for (int j = 0; j < 16; j += 4) {
            float4 a4 = *(const float4*)(al + j);
            An2[j + 0] = -__expf(a4.x) * 1.44269504f;
            An2[j + 1] = -__expf(a4.y) * 1.44269504f;
            An2[j + 2] = -__expf(a4.z) * 1.44269504f;
            An2[j + 3] = -__expf(a4.w) * 1.44269504f;
        }
    }
    __syncthreads();

    float h[16];
#pragma unroll
    for (int n = 0; n < 16; ++n) h[n] = 0.f;
    float dts = 0.f;

    for (int l = 0; l < CL; ++l) {
        const size_t off = (size_t)(mb + l) * 2048 + d;
        const float dtv = dt[off];
        const float xv = bf2f(x_bf[off]);
        const float u = dtv * xv;
        dts += dtv;
        float4 B0 = *(const float4*)&sB[l][0];
        float4 B1 = *(const float4*)&sB[l][4];
        float4 B2 = *(const float4*)&sB[l][8];
        float4 B3 = *(const float4*)&sB[l][12];
        float Bv[16] = {B0.x, B0.y, B0.z, B0.w, B1.x, B1.y, B1.z, B1.w,
                        B2.x, B2.y, B2.z, B2.w, B3.x, B3.y, B3.z, B3.w};
#pragma unroll
        for (int n = 0; n < 16; ++n) {
            const float dA = __builtin_amdgcn_exp2f(dtv * An2[n]);
            h[n] = fmaf(dA, h[n], Bv[n] * u);
        }
    }

    const size_t base = ((size_t)(b * NCK + ck) * 2048 + d) * 16;
#pragma unroll
    for (int j = 0; j < 16; j += 4) {
        float4 pv = make_float4(__builtin_amdgcn_exp2f(dts * An2[j]),
                                __builtin_amdgcn_exp2f(dts * An2[j + 1]),
                                __builtin_amdgcn_exp2f(dts * An2[j + 2]),
                                __builtin_amdgcn_exp2f(dts * An2[j + 3]));
        *(float4*)(Pch + base + j) = pv;
        *(float4*)(Hch + base + j) = make_float4(h[j], h[j + 1], h[j + 2], h[j + 3]);
    }
}

// ---------------- scan combine: serial over chunks; Pch := h_in (in place) ------
__global__ __launch_bounds__(256) void scan_combine(
    float* __restrict__ Pch, const float* __restrict__ Hch)
{
    const int flat = blockIdx.x * 256 + threadIdx.x;   // 2*2048*16
    const int dn = flat & 32767;
    const int b = flat >> 15;
    float hin = 0.f;
#pragma unroll 4
    for (int ck = 0; ck < NCK; ++ck) {
        const size_t a = ((size_t)(b * NCK + ck) << 15) + dn;
        const float p = Pch[a];
        const float hc = Hch[a];
        Pch[a] = hin;
        hin = fmaf(p, hin, hc);
    }
}

// ---------------- scan pass 2: rescan with h_in + fused gating -> y_bf[m][d] ----
__global__ __launch_bounds__(256) void scan_p2(
    const float* __restrict__ dt, const unsigned short* __restrict__ x_bf,
    const float* __restrict__ gate, const float* __restrict__ sp,
    const float* __restrict__ A_log, const float* __restrict__ Dp,
    const float* __restrict__ Hin, unsigned short* __restrict__ y_bf)
{
    __shared__ float sBC[CL][32];
    const int tid = threadIdx.x;
    const int d = blockIdx.x * 256 + tid;
    const int ck = blockIdx.y;
    const int b = blockIdx.z;
    const int mb = b * 1024 + ck * CL;

    {
        int row = tid >> 3, q = (tid & 7) * 4;
        *(float4*)&sBC[row][q] = *(const float4*)(sp + (size_t)(mb + row) * 96 + 64 + q);
    }
    float An2[16];
    {
        const float* al = A_log + d * 16;
#pragma unroll
        for (int j = 0; j < 16; j += 4) {
            float4 a4 = *(const float4*)(al + j);
            An2[j + 0] = -__expf(a4.x) * 1.44269504f;
            An2[j + 1] = -__expf(a4.y) * 1.44269504f;
            An2[j + 2] = -__expf(a4.z) * 1.44269504f;
            An2[j + 3] = -__expf(a4.w) * 1.44269504f;
        }
    }
    float h[16];
    {
        const size_t base = ((size_t)(b * NCK + ck) * 2048 + d) * 16;
#pragma unroll
        for (int j = 0; j < 16; j += 4) {
            float4 hv = *(const float4*)(Hin + base + j);
            h[j] = hv.x; h[j + 1] = hv.y; h[j + 2] = hv.z; h[j + 3] = hv.w;
        }
    }
    const float Dv = Dp[d];
    __syncthreads();

    for (int l = 0; l < CL; ++l) {
        const size_t off = (size_t)(mb + l) * 2048 + d;
        const float dtv = dt[off];
        const float xv = bf2f(x_bf[off]);
        const float gv = gate[off];
        const float u = dtv * xv;
        float4 B0 = *(const float4*)&sBC[l][0];
        float4 B1 = *(const float4*)&sBC[l][4];
        float4 B2 = *(const float4*)&sBC[l][8];
        float4 B3 = *(const float4*)&sBC[l][12];
        float Bv[16] = {B0.x, B0.y, B0.z, B0.w, B1.x, B1.y, B1.z, B1.w,
                        B2.x, B2.y, B2.z, B2.w, B3.x, B3.y, B3.z, B3.w};
#pragma unroll
        for (int n = 0; n < 16; ++n) {
            const float dA = __builtin_amdgcn_exp2f(dtv * An2[n]);
            h[n] = fmaf(dA, h[n], Bv[n] * u);
        }
        float4 C0 = *(const float4*)&sBC[l][16];
        float4 C1 = *(const float4*)&sBC[l][20];
        float4 C2 = *(const float4*)&sBC[l][24];
        float4 C3 = *(const float4*)&sBC[l][28];
        float Cv[16] = {C0.x, C0.y, C0.z, C0.w, C1.x, C1.y, C1.z, C1.w,
                        C2.x, C2.y, C2.z, C2.w, C3.x, C3.y, C3.z, C3.w};
        float p = 0.f;
#pragma unroll
        for (int n = 0; n < 16; ++n)
            p = fmaf(h[n], Cv[n], p);
        y_bf[off] = f2bf(fmaf(xv, Dv, p) * siluf(gv));
    }
}

extern "C" void kernel_launch(void* const* d_in, const int* in_sizes, int n_in,
                              void* d_out, int out_size, void* d_ws, size_t ws_size,
                              hipStream_t stream)
{
    const float* hs     = (const float*)d_in[0];
    const float* W_in   = (const float*)d_in[1];
    const float* conv_w = (const float*)d_in[2];
    const float* conv_b = (const float*)d_in[3];
    const float* W_x    = (const float*)d_in[4];
    const float* W_dt   = (const float*)d_in[5];
    const float* b_dt   = (const float*)d_in[6];
    const float* A_log  = (const float*)d_in[7];
    const float* Dp     = (const float*)d_in[8];
    const float* W_out  = (const float*)d_in[9];
    float* out = (float*)d_out;

    // workspace (~77 MB) with overlays
    float* ws    = (float*)d_ws;
    float* gate  = ws;                               // [2048 m][2048 d] f32
    float* dtb   = gate + (size_t)4194304;           // [2048 m][2048 d] f32
    float* projx = dtb + (size_t)4194304;            // [2048 d][2048 m] f32 (dead after conv)
    float* ssm_p = projx + (size_t)4194304;          // [2048 m][96] f32
    unsigned short* hs_bf    = (unsigned short*)(ssm_p + 196608);   // 2048*1024
    unsigned short* W_in_bf  = hs_bf + (size_t)2097152;             // 4096*1024
    unsigned short* W_out_bf = W_in_bf + (size_t)4194304;           // 1024*2048
    unsigned short* W_x_bf   = W_out_bf + (size_t)2097152;          // 96*2048
    unsigned short* W_dt_bf  = W_x_bf + (size_t)196608;             // 2048*64
    unsigned short* sp64_bf  = W_dt_bf + (size_t)131072;            // 2048*64
    unsigned short* x_bf     = sp64_bf + (size_t)131072;            // [2048 m][2048 d]
    float* Pch = projx;                               // overlay: 2*32*2048*16 f32
    float* Hch = projx + (size_t)2097152;             // overlay
    unsigned short* y_bf = hs_bf;                     // overlay (spans hs_bf+W_in_bf, both dead)

    const int M = B_ * L_;  // 2048

    // 0. fp32 -> bf16 converts
    cvt_bf16<<<(2048 * 1024) / 1024, 256, 0, stream>>>(hs, hs_bf, 2048 * 1024);
    cvt_bf16<<<(4096 * 1024) / 1024, 256, 0, stream>>>(W_in, W_in_bf, 4096 * 1024);
    cvt_bf16<<<(1024 * 2048) / 1024, 256, 0, stream>>>(W_out, W_out_bf, 1024 * 2048);
    cvt_bf16<<<(96 * 2048) / 1024, 256, 0, stream>>>(W_x, W_x_bf, 96 * 2048);
    cvt_bf16<<<(2048 * 64) / 1024, 256, 0, stream>>>(W_dt, W_dt_bf, 2048 * 64);

    // 1. proj GEMM, hybrid epilogue: x-half -> projx[d][m]; gate-half -> gate[m][d]
    gemm_bf16_nt<4><<<dim3(4096 / 128, M / 128, 1), 256, 0, stream>>>(
        hs_bf, W_in_bf, projx, 1024, 4096, 2048, 1024, 4096, nullptr, gate);

    // 2. conv + SiLU -> x_bf[m][d]
    conv_silu_kernel<<<dim3(D_ / 64, L_ / 64, B_), 256, 0, stream>>>(
        projx, conv_w, conv_b, x_bf);

    // 3. ssm_p[m][96] = x @ W_x^T, K=2048 split 8 (bf16 MFMA, atomic fp32)
    hipMemsetAsync(ssm_p, 0, (size_t)M * 96 * sizeof(float), stream);
    gemm_bf16_nt<1><<<dim3(1, M / 128, 8), 256, 0, stream>>>(
        x_bf, W_x_bf, ssm_p, 2048, 96, 96, 256, 96, nullptr, nullptr);

    // 3b. pack dt_lr cols 0..63 -> bf16 [m][64]
    cvt_sp64<<<(2048 * 16) / 256, 256, 0, stream>>>(ssm_p, sp64_bf);

    // 4. dt[m][d] = softplus(dt_lr @ W_dt^T + b_dt[d]) (bf16 MFMA, EPI=3)
    gemm_bf16_nt<3><<<dim3(2048 / 128, M / 128, 1), 256, 0, stream>>>(
        sp64_bf, W_dt_bf, dtb, 64, 2048, 2048, 64, 2048, b_dt, nullptr);

    // 5. scan: pass1 -> combine -> pass2 (writes y_bf[m][d])
    scan_p1<<<dim3(D_ / 256, NCK, B_), 256, 0, stream>>>(
        dtb, x_bf, ssm_p, A_log, Pch, Hch);
    scan_combine<<<(B_ * D_ * 16) / 256, 256, 0, stream>>>(Pch, Hch);
    scan_p2<<<dim3(D_ / 256, NCK, B_), 256, 0, stream>>>(
        dtb, x_bf, gate, ssm_p, A_log, Dp, Pch, y_bf);

    // 6. out = y @ W_out^T : [2048,1024], K=2048 split 2 (bf16 MFMA, atomic fp32)
    hipMemsetAsync(out, 0, (size_t)M * 1024 * sizeof(float), stream);
    gemm_bf16_nt<1><<<dim3(1024 / 128, M / 128, 2), 256, 0, stream>>>(
        y_bf, W_out_bf, out, 2048, 1024, 1024, 1024, 1024, nullptr, nullptr);
}

// Round 7
// 259.548 us; speedup vs baseline: 1.3798x; 1.1464x over previous
//
#include <hip/hip_runtime.h>
#include <hip/hip_bf16.h>
#include <math.h>

#define B_ 2
#define L_ 1024
#define H_ 1024
#define D_ 2048
#define N_ 16
#define R_ 64
#define NCK 32     // chunks per sequence
#define CL 32      // chunk length (NCK*CL == L_)

typedef short short8 __attribute__((ext_vector_type(8)));
typedef float floatx4 __attribute__((ext_vector_type(4)));

__device__ __forceinline__ float siluf(float g) {
    return g / (1.0f + __expf(-g));
}

__device__ __forceinline__ unsigned short f2bf(float f) {
    unsigned int u = __float_as_uint(f);
    u = (u + 0x7fffu + ((u >> 16) & 1u)) >> 16;  // RNE
    return (unsigned short)u;
}

__device__ __forceinline__ float bf2f(unsigned short u) {
    return __uint_as_float(((unsigned int)u) << 16);
}

// async global->LDS, 16B per lane; lds base must be wave-uniform
__device__ __forceinline__ void gl2lds(const unsigned short* g, unsigned short* l) {
    __builtin_amdgcn_global_load_lds(
        (const __attribute__((address_space(1))) unsigned int*)g,
        (__attribute__((address_space(3))) unsigned int*)l, 16, 0, 0);
}

// ---------------- fused fp32 -> bf16 convert for all 5 static tensors ----------------
#define Q0 524288    // hs        2048*1024 /4
#define Q1 1572864   // + W_in    4096*1024 /4
#define Q2 2097152   // + W_out   1024*2048 /4
#define Q3 2146304   // + W_x     96*2048   /4
#define Q4 2179072   // + W_dt    2048*64   /4
__global__ __launch_bounds__(256) void cvt_all(
    const float* __restrict__ i0, const float* __restrict__ i1,
    const float* __restrict__ i2, const float* __restrict__ i3,
    const float* __restrict__ i4,
    unsigned short* __restrict__ o0, unsigned short* __restrict__ o1,
    unsigned short* __restrict__ o2, unsigned short* __restrict__ o3,
    unsigned short* __restrict__ o4)
{
    int q = blockIdx.x * 256 + threadIdx.x;
    if (q >= Q4) return;
    const float* in; unsigned short* out; int base;
    if (q < Q0)      { in = i0; out = o0; base = 0; }
    else if (q < Q1) { in = i1; out = o1; base = Q0; }
    else if (q < Q2) { in = i2; out = o2; base = Q1; }
    else if (q < Q3) { in = i3; out = o3; base = Q2; }
    else             { in = i4; out = o4; base = Q3; }
    int i = (q - base) * 4;
    float4 v = *(const float4*)(in + i);
    ushort4 o;
    o.x = f2bf(v.x); o.y = f2bf(v.y); o.z = f2bf(v.z); o.w = f2bf(v.w);
    *(ushort4*)(out + i) = o;
}

// strided convert: ssm_p[m][96] cols 0..63 -> packed bf16 [m][64]
__global__ __launch_bounds__(256) void cvt_sp64(
    const float* __restrict__ in, unsigned short* __restrict__ out)
{
    int i = blockIdx.x * 256 + threadIdx.x;   // 2048*16 quads
    int m = i >> 4;
    int r = (i & 15) * 4;
    float4 v = *(const float4*)(in + (size_t)m * 96 + r);
    ushort4 o;
    o.x = f2bf(v.x); o.y = f2bf(v.y); o.z = f2bf(v.z); o.w = f2bf(v.w);
    *(ushort4*)(out + (size_t)m * 64 + r) = o;
}

// ---------------- bf16 MFMA GEMM: C = A[M,K] @ B[N,K]^T ----------------
// 128x128 tile, BK=32, 256 threads (4 waves, 2x2 of 64x64), 16x16x32 MFMA,
// global_load_lds width-16 staging. Row strides of A and B must equal K.
// EPI: 0 = plain store C[m][n], 1 = atomicAdd C[m][n] (K-split),
//      4 = proj hybrid: n<2048 -> transposed float4 store C[n][m] (d-major);
//                       n>=2048 -> C2[m][n-2048] m-major store (gate)
template<int EPI>
__global__ __launch_bounds__(256) void gemm_bf16_nt(
    const unsigned short* __restrict__ A, const unsigned short* __restrict__ Bm,
    float* __restrict__ C, int K, int Ncols, int ldc, int kChunk, int nMax,
    float* __restrict__ C2)
{
    __shared__ unsigned short As[128 * 32];
    __shared__ unsigned short Bs[128 * 32];
    const int tid  = threadIdx.x;
    const int lane = tid & 63;
    const int wave = tid >> 6;
    const int wm = (wave >> 1) * 64;
    const int wn = (wave & 1) * 64;
    const int lr   = lane & 15;
    const int quad = lane >> 4;
    const int m0 = blockIdx.y * 128;
    const int n0 = blockIdx.x * 128;
    const int k0 = blockIdx.z * kChunk;

    const int srow = wave * 32 + (lane >> 2);
    const int sq   = (lane & 3) * 8;
    unsigned short* AsB0 = &As[(wave * 32) * 32];
    unsigned short* AsB1 = &As[(wave * 32 + 16) * 32];
    unsigned short* BsB0 = &Bs[(wave * 32) * 32];
    unsigned short* BsB1 = &Bs[(wave * 32 + 16) * 32];
    const size_t aoff0 = (size_t)(m0 + srow) * K + sq;
    const size_t aoff1 = (size_t)(m0 + srow + 16) * K + sq;
    const size_t boff0 = (size_t)min(n0 + srow, nMax - 1) * K + sq;
    const size_t boff1 = (size_t)min(n0 + srow + 16, nMax - 1) * K + sq;

    floatx4 acc[4][4];
#pragma unroll
    for (int mi = 0; mi < 4; ++mi)
#pragma unroll
        for (int ni = 0; ni < 4; ++ni)
            acc[mi][ni] = (floatx4){0.f, 0.f, 0.f, 0.f};

    for (int kt = k0; kt < k0 + kChunk; kt += 32) {
        __syncthreads();
        gl2lds(A + aoff0 + kt, AsB0);
        gl2lds(A + aoff1 + kt, AsB1);
        gl2lds(Bm + boff0 + kt, BsB0);
        gl2lds(Bm + boff1 + kt, BsB1);
        __syncthreads();
        short8 af[4], bf[4];
#pragma unroll
        for (int mi = 0; mi < 4; ++mi)
            af[mi] = *(const short8*)&As[(wm + mi * 16 + lr) * 32 + quad * 8];
#pragma unroll
        for (int ni = 0; ni < 4; ++ni)
            bf[ni] = *(const short8*)&Bs[(wn + ni * 16 + lr) * 32 + quad * 8];
#pragma unroll
        for (int mi = 0; mi < 4; ++mi)
#pragma unroll
            for (int ni = 0; ni < 4; ++ni)
                acc[mi][ni] = __builtin_amdgcn_mfma_f32_16x16x32_bf16(
                    af[mi], bf[ni], acc[mi][ni], 0, 0, 0);
    }

#pragma unroll
    for (int mi = 0; mi < 4; ++mi)
#pragma unroll
        for (int ni = 0; ni < 4; ++ni) {
            const int rr = m0 + wm + mi * 16 + quad * 4;
            const int cc = n0 + wn + ni * 16 + lr;
            if (cc >= Ncols) continue;
            if (EPI == 4) {
                if (n0 < 2048) {
                    float4 v = make_float4(acc[mi][ni][0], acc[mi][ni][1],
                                           acc[mi][ni][2], acc[mi][ni][3]);
                    *(float4*)&C[(size_t)cc * ldc + rr] = v;
                } else {
#pragma unroll
                    for (int r = 0; r < 4; ++r)
                        C2[(size_t)(rr + r) * 2048 + (cc - 2048)] = acc[mi][ni][r];
                }
            } else {
#pragma unroll
                for (int r = 0; r < 4; ++r) {
                    if (EPI == 0)
                        C[(size_t)(rr + r) * ldc + cc] = acc[mi][ni][r];
                    else
                        atomicAdd(&C[(size_t)(rr + r) * ldc + cc], acc[mi][ni][r]);
                }
            }
        }
}

// ---------------- dedicated dt GEMM: dt[m][d] = softplus(sp64 @ W_dt^T + b) -------
// 64x64 tile, 1024 blocks (4/CU), 4 waves (one 16m x 64d strip each), K=64.
// Padded LDS (stride 72) -> conflict-free b128 reads. Fast stable softplus.
__global__ __launch_bounds__(256) void dt_gemm(
    const unsigned short* __restrict__ A,   // sp64_bf [2048 m][64]
    const unsigned short* __restrict__ Bm,  // W_dt_bf [2048 d][64]
    float* __restrict__ C,                  // dt [2048 m][2048 d]
    const float* __restrict__ bias)         // b_dt [2048]
{
    __shared__ unsigned short As[64 * 72];
    __shared__ unsigned short Bs[64 * 72];
    const int tid = threadIdx.x;
    const int lane = tid & 63;
    const int wave = tid >> 6;
    const int lr = lane & 15;
    const int quad = lane >> 4;
    const int n0 = blockIdx.x * 64;
    const int m0 = blockIdx.y * 64;

    // staging: 256 threads, each stages one 16B chunk of A and B
    {
        const int row = tid >> 3;          // 0..31 (two passes cover 64 rows)
        const int cq = (tid & 7) * 8;
        uint4 a0 = *(const uint4*)(A + (size_t)(m0 + row) * 64 + cq);
        uint4 a1 = *(const uint4*)(A + (size_t)(m0 + 32 + row) * 64 + cq);
        uint4 b0 = *(const uint4*)(Bm + (size_t)(n0 + row) * 64 + cq);
        uint4 b1 = *(const uint4*)(Bm + (size_t)(n0 + 32 + row) * 64 + cq);
        *(uint4*)&As[row * 72 + cq] = a0;
        *(uint4*)&As[(32 + row) * 72 + cq] = a1;
        *(uint4*)&Bs[row * 72 + cq] = b0;
        *(uint4*)&Bs[(32 + row) * 72 + cq] = b1;
    }
    __syncthreads();

    floatx4 acc[4];
#pragma unroll
    for (int ni = 0; ni < 4; ++ni) acc[ni] = (floatx4){0.f, 0.f, 0.f, 0.f};

#pragma unroll
    for (int kt = 0; kt < 64; kt += 32) {
        short8 af = *(const short8*)&As[(wave * 16 + lr) * 72 + kt + quad * 8];
#pragma unroll
        for (int ni = 0; ni < 4; ++ni) {
            short8 bf = *(const short8*)&Bs[(ni * 16 + lr) * 72 + kt + quad * 8];
            acc[ni] = __builtin_amdgcn_mfma_f32_16x16x32_bf16(af, bf, acc[ni], 0, 0, 0);
        }
    }

    const int rr = m0 + wave * 16 + quad * 4;
#pragma unroll
    for (int ni = 0; ni < 4; ++ni) {
        const int cc = n0 + ni * 16 + lr;
        const float bv = bias[cc];
#pragma unroll
        for (int r = 0; r < 4; ++r) {
            const float z = acc[ni][r] + bv;
            const float spv = fmaxf(z, 0.f) + __logf(1.f + __expf(-fabsf(z)));
            C[(size_t)(rr + r) * 2048 + cc] = spv;
        }
    }
}

// ---------------- causal depthwise conv (K=4) + bias + SiLU, d-major in ----------------
// reads projx[d][m] rows (contiguous), writes x_bf[m][d] bf16 (LDS transpose)
__global__ __launch_bounds__(256) void conv_silu_kernel(
    const float* __restrict__ projx, const float* __restrict__ conv_w,
    const float* __restrict__ conv_b, unsigned short* __restrict__ x_bf)
{
    __shared__ unsigned short tile[64][72];
    const int t = threadIdx.x;
    const int d0 = blockIdx.x * 64;
    const int lt0 = blockIdx.y * 64;
    const int b = blockIdx.z;
    const int dl = t & 63;
    const int seg = t >> 6;
    const int d = d0 + dl;
    const int l0 = lt0 + seg * 16;
    const float* row = projx + (size_t)d * 2048 + b * 1024;
    const float w0 = conv_w[d * 4 + 0], w1 = conv_w[d * 4 + 1];
    const float w2 = conv_w[d * 4 + 2], w3 = conv_w[d * 4 + 3];
    const float bias = conv_b[d];

    float p[19];
    p[0] = (l0 >= 3) ? row[l0 - 3] : 0.f;
    p[1] = (l0 >= 2) ? row[l0 - 2] : 0.f;
    p[2] = (l0 >= 1) ? row[l0 - 1] : 0.f;
#pragma unroll
    for (int j = 0; j < 16; j += 4) {
        float4 q = *(const float4*)(row + l0 + j);
        p[3 + j] = q.x; p[4 + j] = q.y; p[5 + j] = q.z; p[6 + j] = q.w;
    }
#pragma unroll
    for (int j = 0; j < 16; ++j) {
        float v = siluf(bias + w0 * p[j] + w1 * p[j + 1] + w2 * p[j + 2] + w3 * p[j + 3]);
        tile[seg * 16 + j][dl] = f2bf(v);
    }
    __syncthreads();

    const int ml = t >> 2;
    const int c = t & 3;
    short8 s0 = *(const short8*)&tile[ml][c * 16];
    short8 s1 = *(const short8*)&tile[ml][c * 16 + 8];
    unsigned short* dst = x_bf + (size_t)(b * 1024 + lt0 + ml) * 2048 + d0 + c * 16;
    *(short8*)dst = s0;
    *(short8*)(dst + 8) = s1;
}

// ---------------- scan pass 1: per-chunk P[n], H[n] (from h=0) ----------------
__global__ __launch_bounds__(256) void scan_p1(
    const float* __restrict__ dt, const unsigned short* __restrict__ x_bf,
    const float* __restrict__ sp, const float* __restrict__ A_log,
    float* __restrict__ Pch, float* __restrict__ Hch)
{
    __shared__ float sB[CL][16];
    const int tid = threadIdx.x;
    const int d = blockIdx.x * 256 + tid;
    const int ck = blockIdx.y;
    const int b = blockIdx.z;
    const int mb = b * 1024 + ck * CL;

    if (tid < CL * 4) {
        int row = tid >> 2, q = (tid & 3) * 4;
        *(float4*)&sB[row][q] = *(const float4*)(sp + (size_t)(mb + row) * 96 + 64 + q);
    }
    float An2[16];
    {
        const float* al = A_log + d * 16;
#pragma unroll
        for (int j = 0; j < 16; j += 4) {
            float4 a4 = *(const float4*)(al + j);
            An2[j + 0] = -__expf(a4.x) * 1.44269504f;
            An2[j + 1] = -__expf(a4.y) * 1.44269504f;
            An2[j + 2] = -__expf(a4.z) * 1.44269504f;
            An2[j + 3] = -__expf(a4.w) * 1.44269504f;
        }
    }
    __syncthreads();

    float h[16];
#pragma unroll
    for (int n = 0; n < 16; ++n) h[n] = 0.f;
    float dts = 0.f;

    for (int l = 0; l < CL; ++l) {
        const size_t off = (size_t)(mb + l) * 2048 + d;
        const float dtv = dt[off];
        const float xv = bf2f(x_bf[off]);
        const float u = dtv * xv;
        dts += dtv;
        float4 B0 = *(const float4*)&sB[l][0];
        float4 B1 = *(const float4*)&sB[l][4];
        float4 B2 = *(const float4*)&sB[l][8];
        float4 B3 = *(const float4*)&sB[l][12];
        float Bv[16] = {B0.x, B0.y, B0.z, B0.w, B1.x, B1.y, B1.z, B1.w,
                        B2.x, B2.y, B2.z, B2.w, B3.x, B3.y, B3.z, B3.w};
#pragma unroll
        for (int n = 0; n < 16; ++n) {
            const float dA = __builtin_amdgcn_exp2f(dtv * An2[n]);
            h[n] = fmaf(dA, h[n], Bv[n] * u);
        }
    }

    const size_t base = ((size_t)(b * NCK + ck) * 2048 + d) * 16;
#pragma unroll
    for (int j = 0; j < 16; j += 4) {
        float4 pv = make_float4(__builtin_amdgcn_exp2f(dts * An2[j]),
                                __builtin_amdgcn_exp2f(dts * An2[j + 1]),
                                __builtin_amdgcn_exp2f(dts * An2[j + 2]),
                                __builtin_amdgcn_exp2f(dts * An2[j + 3]));
        *(float4*)(Pch + base + j) = pv;
        *(float4*)(Hch + base + j) = make_float4(h[j], h[j + 1], h[j + 2], h[j + 3]);
    }
}

// ---------------- scan combine: serial over chunks; Pch := h_in (in place) ------
__global__ __launch_bounds__(256) void scan_combine(
    float* __restrict__ Pch, const float* __restrict__ Hch)
{
    const int flat = blockIdx.x * 256 + threadIdx.x;   // 2*2048*16
    const int dn = flat & 32767;
    const int b = flat >> 15;
    float hin = 0.f;
#pragma unroll 4
    for (int ck = 0; ck < NCK; ++ck) {
        const size_t a = ((size_t)(b * NCK + ck) << 15) + dn;
        const float p = Pch[a];
        const float hc = Hch[a];
        Pch[a] = hin;
        hin = fmaf(p, hin, hc);
    }
}

// ---------------- scan pass 2: rescan with h_in + fused gating -> y_bf[m][d] ----
__global__ __launch_bounds__(256) void scan_p2(
    const float* __restrict__ dt, const unsigned short* __restrict__ x_bf,
    const float* __restrict__ gate, const float* __restrict__ sp,
    const float* __restrict__ A_log, const float* __restrict__ Dp,
    const float* __restrict__ Hin, unsigned short* __restrict__ y_bf)
{
    __shared__ float sBC[CL][32];
    const int tid = threadIdx.x;
    const int d = blockIdx.x * 256 + tid;
    const int ck = blockIdx.y;
    const int b = blockIdx.z;
    const int mb = b * 1024 + ck * CL;

    {
        int row = tid >> 3, q = (tid & 7) * 4;
        *(float4*)&sBC[row][q] = *(const float4*)(sp + (size_t)(mb + row) * 96 + 64 + q);
    }
    float An2[16];
    {
        const float* al = A_log + d * 16;
#pragma unroll
        for (int j = 0; j < 16; j += 4) {
            float4 a4 = *(const float4*)(al + j);
            An2[j + 0] = -__expf(a4.x) * 1.44269504f;
            An2[j + 1] = -__expf(a4.y) * 1.44269504f;
            An2[j + 2] = -__expf(a4.z) * 1.44269504f;
            An2[j + 3] = -__expf(a4.w) * 1.44269504f;
        }
    }
    float h[16];
    {
        const size_t base = ((size_t)(b * NCK + ck) * 2048 + d) * 16;
#pragma unroll
        for (int j = 0; j < 16; j += 4) {
            float4 hv = *(const float4*)(Hin + base + j);
            h[j] = hv.x; h[j + 1] = hv.y; h[j + 2] = hv.z; h[j + 3] = hv.w;
        }
    }
    const float Dv = Dp[d];
    __syncthreads();

    for (int l = 0; l < CL; ++l) {
        const size_t off = (size_t)(mb + l) * 2048 + d;
        const float dtv = dt[off];
        const float xv = bf2f(x_bf[off]);
        const float gv = gate[off];
        const float u = dtv * xv;
        float4 B0 = *(const float4*)&sBC[l][0];
        float4 B1 = *(const float4*)&sBC[l][4];
        float4 B2 = *(const float4*)&sBC[l][8];
        float4 B3 = *(const float4*)&sBC[l][12];
        float Bv[16] = {B0.x, B0.y, B0.z, B0.w, B1.x, B1.y, B1.z, B1.w,
                        B2.x, B2.y, B2.z, B2.w, B3.x, B3.y, B3.z, B3.w};
#pragma unroll
        for (int n = 0; n < 16; ++n) {
            const float dA = __builtin_amdgcn_exp2f(dtv * An2[n]);
            h[n] = fmaf(dA, h[n], Bv[n] * u);
        }
        float4 C0 = *(const float4*)&sBC[l][16];
        float4 C1 = *(const float4*)&sBC[l][20];
        float4 C2 = *(const float4*)&sBC[l][24];
        float4 C3 = *(const float4*)&sBC[l][28];
        float Cv[16] = {C0.x, C0.y, C0.z, C0.w, C1.x, C1.y, C1.z, C1.w,
                        C2.x, C2.y, C2.z, C2.w, C3.x, C3.y, C3.z, C3.w};
        float p = 0.f;
#pragma unroll
        for (int n = 0; n < 16; ++n)
            p = fmaf(h[n], Cv[n], p);
        y_bf[off] = f2bf(fmaf(xv, Dv, p) * siluf(gv));
    }
}

extern "C" void kernel_launch(void* const* d_in, const int* in_sizes, int n_in,
                              void* d_out, int out_size, void* d_ws, size_t ws_size,
                              hipStream_t stream)
{
    const float* hs     = (const float*)d_in[0];
    const float* W_in   = (const float*)d_in[1];
    const float* conv_w = (const float*)d_in[2];
    const float* conv_b = (const float*)d_in[3];
    const float* W_x    = (const float*)d_in[4];
    const float* W_dt   = (const float*)d_in[5];
    const float* b_dt   = (const float*)d_in[6];
    const float* A_log  = (const float*)d_in[7];
    const float* Dp     = (const float*)d_in[8];
    const float* W_out  = (const float*)d_in[9];
    float* out = (float*)d_out;

    // workspace (~77 MB) with overlays
    float* ws    = (float*)d_ws;
    float* gate  = ws;                               // [2048 m][2048 d] f32
    float* dtb   = gate + (size_t)4194304;           // [2048 m][2048 d] f32
    float* projx = dtb + (size_t)4194304;            // [2048 d][2048 m] f32 (dead after conv)
    float* ssm_p = projx + (size_t)4194304;          // [2048 m][96] f32
    unsigned short* hs_bf    = (unsigned short*)(ssm_p + 196608);   // 2048*1024
    unsigned short* W_in_bf  = hs_bf + (size_t)2097152;             // 4096*1024
    unsigned short* W_out_bf = W_in_bf + (size_t)4194304;           // 1024*2048
    unsigned short* W_x_bf   = W_out_bf + (size_t)2097152;          // 96*2048
    unsigned short* W_dt_bf  = W_x_bf + (size_t)196608;             // 2048*64
    unsigned short* sp64_bf  = W_dt_bf + (size_t)131072;            // 2048*64
    unsigned short* x_bf     = sp64_bf + (size_t)131072;            // [2048 m][2048 d]
    float* Pch = projx;                               // overlay: 2*32*2048*16 f32
    float* Hch = projx + (size_t)2097152;             // overlay
    unsigned short* y_bf = hs_bf;                     // overlay (spans hs_bf+W_in_bf, both dead)

    const int M = B_ * L_;  // 2048

    // 0. fused fp32 -> bf16 converts (hs, W_in, W_out, W_x, W_dt)
    cvt_all<<<(Q4 + 255) / 256, 256, 0, stream>>>(
        hs, W_in, W_out, W_x, W_dt, hs_bf, W_in_bf, W_out_bf, W_x_bf, W_dt_bf);

    // 1. proj GEMM, hybrid epilogue: x-half -> projx[d][m]; gate-half -> gate[m][d]
    gemm_bf16_nt<4><<<dim3(4096 / 128, M / 128, 1), 256, 0, stream>>>(
        hs_bf, W_in_bf, projx, 1024, 4096, 2048, 1024, 4096, gate);

    // 2. conv + SiLU -> x_bf[m][d]
    conv_silu_kernel<<<dim3(D_ / 64, L_ / 64, B_), 256, 0, stream>>>(
        projx, conv_w, conv_b, x_bf);

    // 3. ssm_p[m][96] = x @ W_x^T, K=2048 split 16 (bf16 MFMA, atomic fp32)
    hipMemsetAsync(ssm_p, 0, (size_t)M * 96 * sizeof(float), stream);
    gemm_bf16_nt<1><<<dim3(1, M / 128, 16), 256, 0, stream>>>(
        x_bf, W_x_bf, ssm_p, 2048, 96, 96, 128, 96, nullptr);

    // 3b. pack dt_lr cols 0..63 -> bf16 [m][64]
    cvt_sp64<<<(2048 * 16) / 256, 256, 0, stream>>>(ssm_p, sp64_bf);

    // 4. dt[m][d] = softplus(dt_lr @ W_dt^T + b_dt[d]) — dedicated 64x64 kernel
    dt_gemm<<<dim3(2048 / 64, 2048 / 64), 256, 0, stream>>>(
        sp64_bf, W_dt_bf, dtb, b_dt);

    // 5. scan: pass1 -> combine -> pass2 (writes y_bf[m][d])
    scan_p1<<<dim3(D_ / 256, NCK, B_), 256, 0, stream>>>(
        dtb, x_bf, ssm_p, A_log, Pch, Hch);
    scan_combine<<<(B_ * D_ * 16) / 256, 256, 0, stream>>>(Pch, Hch);
    scan_p2<<<dim3(D_ / 256, NCK, B_), 256, 0, stream>>>(
        dtb, x_bf, gate, ssm_p, A_log, Dp, Pch, y_bf);

    // 6. out = y @ W_out^T : [2048,1024], K=2048 split 4 (bf16 MFMA, atomic fp32)
    hipMemsetAsync(out, 0, (size_t)M * 1024 * sizeof(float), stream);
    gemm_bf16_nt<1><<<dim3(1024 / 128, M / 128, 4), 256, 0, stream>>>(
        y_bf, W_out_bf, out, 2048, 1024, 1024, 512, 1024, nullptr);
}

// Round 8
// 236.985 us; speedup vs baseline: 1.5111x; 1.0952x over previous
//
#include <hip/hip_runtime.h>
#include <hip/hip_bf16.h>
#include <math.h>

#define B_ 2
#define L_ 1024
#define H_ 1024
#define D_ 2048
#define N_ 16
#define R_ 64
#define NCK 32     // chunks per sequence
#define CL 32      // chunk length (NCK*CL == L_)

typedef short short8 __attribute__((ext_vector_type(8)));
typedef float floatx4 __attribute__((ext_vector_type(4)));

__device__ __forceinline__ float siluf(float g) {
    return g / (1.0f + __expf(-g));
}

__device__ __forceinline__ unsigned short f2bf(float f) {
    unsigned int u = __float_as_uint(f);
    u = (u + 0x7fffu + ((u >> 16) & 1u)) >> 16;  // RNE
    return (unsigned short)u;
}

__device__ __forceinline__ float bf2f(unsigned short u) {
    return __uint_as_float(((unsigned int)u) << 16);
}

// async global->LDS, 16B per lane; lds base must be wave-uniform
__device__ __forceinline__ void gl2lds(const unsigned short* g, unsigned short* l) {
    __builtin_amdgcn_global_load_lds(
        (const __attribute__((address_space(1))) unsigned int*)g,
        (__attribute__((address_space(3))) unsigned int*)l, 16, 0, 0);
}

// ---------------- fused fp32 -> bf16 convert for all 5 static tensors ----------------
#define Q0 524288    // hs        2048*1024 /4
#define Q1 1572864   // + W_in    4096*1024 /4
#define Q2 2097152   // + W_out   1024*2048 /4
#define Q3 2146304   // + W_x     96*2048   /4
#define Q4 2179072   // + W_dt    2048*64   /4
__global__ __launch_bounds__(256) void cvt_all(
    const float* __restrict__ i0, const float* __restrict__ i1,
    const float* __restrict__ i2, const float* __restrict__ i3,
    const float* __restrict__ i4,
    unsigned short* __restrict__ o0, unsigned short* __restrict__ o1,
    unsigned short* __restrict__ o2, unsigned short* __restrict__ o3,
    unsigned short* __restrict__ o4)
{
    int q = blockIdx.x * 256 + threadIdx.x;
    if (q >= Q4) return;
    const float* in; unsigned short* out; int base;
    if (q < Q0)      { in = i0; out = o0; base = 0; }
    else if (q < Q1) { in = i1; out = o1; base = Q0; }
    else if (q < Q2) { in = i2; out = o2; base = Q1; }
    else if (q < Q3) { in = i3; out = o3; base = Q2; }
    else             { in = i4; out = o4; base = Q3; }
    int i = (q - base) * 4;
    float4 v = *(const float4*)(in + i);
    ushort4 o;
    o.x = f2bf(v.x); o.y = f2bf(v.y); o.z = f2bf(v.z); o.w = f2bf(v.w);
    *(ushort4*)(out + i) = o;
}

// ---------------- bf16 MFMA GEMM: C = A[M,K] @ B[N,K]^T ----------------
// 128x128 tile, BK=32, 256 threads (4 waves, 2x2 of 64x64), 16x16x32 MFMA,
// global_load_lds width-16 staging. Row strides of A and B must equal K.
// EPI: 0 = plain store C[z*partStride + m*ldc + n] (split-K partials),
//      4 = proj hybrid: n<2048 -> transposed float4 store C[n][m] (d-major);
//                       n>=2048 -> C2[m][n-2048] m-major store (gate)
template<int EPI>
__global__ __launch_bounds__(256) void gemm_bf16_nt(
    const unsigned short* __restrict__ A, const unsigned short* __restrict__ Bm,
    float* __restrict__ C, int K, int Ncols, int ldc, int kChunk, int nMax,
    size_t partStride, float* __restrict__ C2)
{
    __shared__ unsigned short As[128 * 32];
    __shared__ unsigned short Bs[128 * 32];
    const int tid  = threadIdx.x;
    const int lane = tid & 63;
    const int wave = tid >> 6;
    const int wm = (wave >> 1) * 64;
    const int wn = (wave & 1) * 64;
    const int lr   = lane & 15;
    const int quad = lane >> 4;
    const int m0 = blockIdx.y * 128;
    const int n0 = blockIdx.x * 128;
    const int k0 = blockIdx.z * kChunk;

    const int srow = wave * 32 + (lane >> 2);
    const int sq   = (lane & 3) * 8;
    unsigned short* AsB0 = &As[(wave * 32) * 32];
    unsigned short* AsB1 = &As[(wave * 32 + 16) * 32];
    unsigned short* BsB0 = &Bs[(wave * 32) * 32];
    unsigned short* BsB1 = &Bs[(wave * 32 + 16) * 32];
    const size_t aoff0 = (size_t)(m0 + srow) * K + sq;
    const size_t aoff1 = (size_t)(m0 + srow + 16) * K + sq;
    const size_t boff0 = (size_t)min(n0 + srow, nMax - 1) * K + sq;
    const size_t boff1 = (size_t)min(n0 + srow + 16, nMax - 1) * K + sq;

    floatx4 acc[4][4];
#pragma unroll
    for (int mi = 0; mi < 4; ++mi)
#pragma unroll
        for (int ni = 0; ni < 4; ++ni)
            acc[mi][ni] = (floatx4){0.f, 0.f, 0.f, 0.f};

    for (int kt = k0; kt < k0 + kChunk; kt += 32) {
        __syncthreads();
        gl2lds(A + aoff0 + kt, AsB0);
        gl2lds(A + aoff1 + kt, AsB1);
        gl2lds(Bm + boff0 + kt, BsB0);
        gl2lds(Bm + boff1 + kt, BsB1);
        __syncthreads();
        short8 af[4], bf[4];
#pragma unroll
        for (int mi = 0; mi < 4; ++mi)
            af[mi] = *(const short8*)&As[(wm + mi * 16 + lr) * 32 + quad * 8];
#pragma unroll
        for (int ni = 0; ni < 4; ++ni)
            bf[ni] = *(const short8*)&Bs[(wn + ni * 16 + lr) * 32 + quad * 8];
#pragma unroll
        for (int mi = 0; mi < 4; ++mi)
#pragma unroll
            for (int ni = 0; ni < 4; ++ni)
                acc[mi][ni] = __builtin_amdgcn_mfma_f32_16x16x32_bf16(
                    af[mi], bf[ni], acc[mi][ni], 0, 0, 0);
    }

    float* Cz = C + (size_t)blockIdx.z * partStride;
#pragma unroll
    for (int mi = 0; mi < 4; ++mi)
#pragma unroll
        for (int ni = 0; ni < 4; ++ni) {
            const int rr = m0 + wm + mi * 16 + quad * 4;
            const int cc = n0 + wn + ni * 16 + lr;
            if (cc >= Ncols) continue;
            if (EPI == 4) {
                if (n0 < 2048) {
                    float4 v = make_float4(acc[mi][ni][0], acc[mi][ni][1],
                                           acc[mi][ni][2], acc[mi][ni][3]);
                    *(float4*)&C[(size_t)cc * ldc + rr] = v;
                } else {
#pragma unroll
                    for (int r = 0; r < 4; ++r)
                        C2[(size_t)(rr + r) * 2048 + (cc - 2048)] = acc[mi][ni][r];
                }
            } else {
#pragma unroll
                for (int r = 0; r < 4; ++r)
                    Cz[(size_t)(rr + r) * ldc + cc] = acc[mi][ni][r];
            }
        }
}

// ---------------- reduce 16 ssm partials -> ssm_p[m][96] + sp64_bf[m][64] ----------------
__global__ __launch_bounds__(256) void reduce_ssm(
    const float* __restrict__ P, float* __restrict__ ssm_p,
    unsigned short* __restrict__ sp64)
{
    const int q = blockIdx.x * 256 + threadIdx.x;    // 2048*24 quads
    const int m = q / 24;
    const int c = (q - m * 24) * 4;
    const size_t idx = (size_t)m * 96 + c;
    float4 s = make_float4(0.f, 0.f, 0.f, 0.f);
#pragma unroll
    for (int z = 0; z < 16; ++z) {
        float4 v = *(const float4*)(P + (size_t)z * (2048 * 96) + idx);
        s.x += v.x; s.y += v.y; s.z += v.z; s.w += v.w;
    }
    *(float4*)(ssm_p + idx) = s;
    if (c < 64) {
        ushort4 o;
        o.x = f2bf(s.x); o.y = f2bf(s.y); o.z = f2bf(s.z); o.w = f2bf(s.w);
        *(ushort4*)(sp64 + (size_t)m * 64 + c) = o;
    }
}

// ---------------- reduce 4 out partials -> out[m][h] ----------------
__global__ __launch_bounds__(256) void reduce_out(
    const float* __restrict__ P, float* __restrict__ out)
{
    const size_t i = ((size_t)blockIdx.x * 256 + threadIdx.x) * 4;  // 2048*1024 total
    float4 a = *(const float4*)(P + i);
    float4 b = *(const float4*)(P + 2097152 + i);
    float4 c = *(const float4*)(P + 2 * 2097152 + i);
    float4 d = *(const float4*)(P + 3 * 2097152 + i);
    *(float4*)(out + i) = make_float4(a.x + b.x + c.x + d.x,
                                      a.y + b.y + c.y + d.y,
                                      a.z + b.z + c.z + d.z,
                                      a.w + b.w + c.w + d.w);
}

// ---------------- dedicated dt GEMM: dt[m][d] = softplus(sp64 @ W_dt^T + b) -------
__global__ __launch_bounds__(256) void dt_gemm(
    const unsigned short* __restrict__ A,   // sp64_bf [2048 m][64]
    const unsigned short* __restrict__ Bm,  // W_dt_bf [2048 d][64]
    float* __restrict__ C,                  // dt [2048 m][2048 d]
    const float* __restrict__ bias)         // b_dt [2048]
{
    __shared__ unsigned short As[64 * 72];
    __shared__ unsigned short Bs[64 * 72];
    const int tid = threadIdx.x;
    const int lane = tid & 63;
    const int wave = tid >> 6;
    const int lr = lane & 15;
    const int quad = lane >> 4;
    const int n0 = blockIdx.x * 64;
    const int m0 = blockIdx.y * 64;

    {
        const int row = tid >> 3;
        const int cq = (tid & 7) * 8;
        uint4 a0 = *(const uint4*)(A + (size_t)(m0 + row) * 64 + cq);
        uint4 a1 = *(const uint4*)(A + (size_t)(m0 + 32 + row) * 64 + cq);
        uint4 b0 = *(const uint4*)(Bm + (size_t)(n0 + row) * 64 + cq);
        uint4 b1 = *(const uint4*)(Bm + (size_t)(n0 + 32 + row) * 64 + cq);
        *(uint4*)&As[row * 72 + cq] = a0;
        *(uint4*)&As[(32 + row) * 72 + cq] = a1;
        *(uint4*)&Bs[row * 72 + cq] = b0;
        *(uint4*)&Bs[(32 + row) * 72 + cq] = b1;
    }
    __syncthreads();

    floatx4 acc[4];
#pragma unroll
    for (int ni = 0; ni < 4; ++ni) acc[ni] = (floatx4){0.f, 0.f, 0.f, 0.f};

#pragma unroll
    for (int kt = 0; kt < 64; kt += 32) {
        short8 af = *(const short8*)&As[(wave * 16 + lr) * 72 + kt + quad * 8];
#pragma unroll
        for (int ni = 0; ni < 4; ++ni) {
            short8 bf = *(const short8*)&Bs[(ni * 16 + lr) * 72 + kt + quad * 8];
            acc[ni] = __builtin_amdgcn_mfma_f32_16x16x32_bf16(af, bf, acc[ni], 0, 0, 0);
        }
    }

    const int rr = m0 + wave * 16 + quad * 4;
#pragma unroll
    for (int ni = 0; ni < 4; ++ni) {
        const int cc = n0 + ni * 16 + lr;
        const float bv = bias[cc];
#pragma unroll
        for (int r = 0; r < 4; ++r) {
            const float z = acc[ni][r] + bv;
            const float spv = fmaxf(z, 0.f) + __logf(1.f + __expf(-fabsf(z)));
            C[(size_t)(rr + r) * 2048 + cc] = spv;
        }
    }
}

// ---------------- causal depthwise conv (K=4) + bias + SiLU, d-major in ----------------
__global__ __launch_bounds__(256) void conv_silu_kernel(
    const float* __restrict__ projx, const float* __restrict__ conv_w,
    const float* __restrict__ conv_b, unsigned short* __restrict__ x_bf)
{
    __shared__ unsigned short tile[64][72];
    const int t = threadIdx.x;
    const int d0 = blockIdx.x * 64;
    const int lt0 = blockIdx.y * 64;
    const int b = blockIdx.z;
    const int dl = t & 63;
    const int seg = t >> 6;
    const int d = d0 + dl;
    const int l0 = lt0 + seg * 16;
    const float* row = projx + (size_t)d * 2048 + b * 1024;
    const float w0 = conv_w[d * 4 + 0], w1 = conv_w[d * 4 + 1];
    const float w2 = conv_w[d * 4 + 2], w3 = conv_w[d * 4 + 3];
    const float bias = conv_b[d];

    float p[19];
    p[0] = (l0 >= 3) ? row[l0 - 3] : 0.f;
    p[1] = (l0 >= 2) ? row[l0 - 2] : 0.f;
    p[2] = (l0 >= 1) ? row[l0 - 1] : 0.f;
#pragma unroll
    for (int j = 0; j < 16; j += 4) {
        float4 q = *(const float4*)(row + l0 + j);
        p[3 + j] = q.x; p[4 + j] = q.y; p[5 + j] = q.z; p[6 + j] = q.w;
    }
#pragma unroll
    for (int j = 0; j < 16; ++j) {
        float v = siluf(bias + w0 * p[j] + w1 * p[j + 1] + w2 * p[j + 2] + w3 * p[j + 3]);
        tile[seg * 16 + j][dl] = f2bf(v);
    }
    __syncthreads();

    const int ml = t >> 2;
    const int c = t & 3;
    short8 s0 = *(const short8*)&tile[ml][c * 16];
    short8 s1 = *(const short8*)&tile[ml][c * 16 + 8];
    unsigned short* dst = x_bf + (size_t)(b * 1024 + lt0 + ml) * 2048 + d0 + c * 16;
    *(short8*)dst = s0;
    *(short8*)(dst + 8) = s1;
}

// ---------------- scan pass 1: per-chunk P[n], H[n] (from h=0) ----------------
__global__ __launch_bounds__(256) void scan_p1(
    const float* __restrict__ dt, const unsigned short* __restrict__ x_bf,
    const float* __restrict__ sp, const float* __restrict__ A_log,
    float* __restrict__ Pch, float* __restrict__ Hch)
{
    __shared__ float sB[CL][16];
    const int tid = threadIdx.x;
    const int d = blockIdx.x * 256 + tid;
    const int ck = blockIdx.y;
    const int b = blockIdx.z;
    const int mb = b * 1024 + ck * CL;

    if (tid < CL * 4) {
        int row = tid >> 2, q = (tid & 3) * 4;
        *(float4*)&sB[row][q] = *(const float4*)(sp + (size_t)(mb + row) * 96 + 64 + q);
    }
    float An2[16];
    {
        const float* al = A_log + d * 16;
#pragma unroll
        for (int j = 0; j < 16; j += 4) {
            float4 a4 = *(const float4*)(al + j);
            An2[j + 0] = -__expf(a4.x) * 1.44269504f;
            An2[j + 1] = -__expf(a4.y) * 1.44269504f;
            An2[j + 2] = -__expf(a4.z) * 1.44269504f;
            An2[j + 3] = -__expf(a4.w) * 1.44269504f;
        }
    }
    __syncthreads();

    float h[16];
#pragma unroll
    for (int n = 0; n < 16; ++n) h[n] = 0.f;
    float dts = 0.f;

    for (int l = 0; l < CL; ++l) {
        const size_t off = (size_t)(mb + l) * 2048 + d;
        const float dtv = dt[off];
        const float xv = bf2f(x_bf[off]);
        const float u = dtv * xv;
        dts += dtv;
        float4 B0 = *(const float4*)&sB[l][0];
        float4 B1 = *(const float4*)&sB[l][4];
        float4 B2 = *(const float4*)&sB[l][8];
        float4 B3 = *(const float4*)&sB[l][12];
        float Bv[16] = {B0.x, B0.y, B0.z, B0.w, B1.x, B1.y, B1.z, B1.w,
                        B2.x, B2.y, B2.z, B2.w, B3.x, B3.y, B3.z, B3.w};
#pragma unroll
        for (int n = 0; n < 16; ++n) {
            const float dA = __builtin_amdgcn_exp2f(dtv * An2[n]);
            h[n] = fmaf(dA, h[n], Bv[n] * u);
        }
    }

    const size_t base = ((size_t)(b * NCK + ck) * 2048 + d) * 16;
#pragma unroll
    for (int j = 0; j < 16; j += 4) {
        float4 pv = make_float4(__builtin_amdgcn_exp2f(dts * An2[j]),
                                __builtin_amdgcn_exp2f(dts * An2[j + 1]),
                                __builtin_amdgcn_exp2f(dts * An2[j + 2]),
                                __builtin_amdgcn_exp2f(dts * An2[j + 3]));
        *(float4*)(Pch + base + j) = pv;
        *(float4*)(Hch + base + j) = make_float4(h[j], h[j + 1], h[j + 2], h[j + 3]);
    }
}

// ---------------- scan combine: serial over chunks; Pch := h_in (in place) ------
__global__ __launch_bounds__(256) void scan_combine(
    float* __restrict__ Pch, const float* __restrict__ Hch)
{
    const int flat = blockIdx.x * 256 + threadIdx.x;   // 2*2048*16
    const int dn = flat & 32767;
    const int b = flat >> 15;
    float hin = 0.f;
#pragma unroll 4
    for (int ck = 0; ck < NCK; ++ck) {
        const size_t a = ((size_t)(b * NCK + ck) << 15) + dn;
        const float p = Pch[a];
        const float hc = Hch[a];
        Pch[a] = hin;
        hin = fmaf(p, hin, hc);
    }
}

// ---------------- scan pass 2: rescan with h_in + fused gating -> y_bf[m][d] ----
__global__ __launch_bounds__(256) void scan_p2(
    const float* __restrict__ dt, const unsigned short* __restrict__ x_bf,
    const float* __restrict__ gate, const float* __restrict__ sp,
    const float* __restrict__ A_log, const float* __restrict__ Dp,
    const float* __restrict__ Hin, unsigned short* __restrict__ y_bf)
{
    __shared__ float sBC[CL][32];
    const int tid = threadIdx.x;
    const int d = blockIdx.x * 256 + tid;
    const int ck = blockIdx.y;
    const int b = blockIdx.z;
    const int mb = b * 1024 + ck * CL;

    {
        int row = tid >> 3, q = (tid & 7) * 4;
        *(float4*)&sBC[row][q] = *(const float4*)(sp + (size_t)(mb + row) * 96 + 64 + q);
    }
    float An2[16];
    {
        const float* al = A_log + d * 16;
#pragma unroll
        for (int j = 0; j < 16; j += 4) {
            float4 a4 = *(const float4*)(al + j);
            An2[j + 0] = -__expf(a4.x) * 1.44269504f;
            An2[j + 1] = -__expf(a4.y) * 1.44269504f;
            An2[j + 2] = -__expf(a4.z) * 1.44269504f;
            An2[j + 3] = -__expf(a4.w) * 1.44269504f;
        }
    }
    float h[16];
    {
        const size_t base = ((size_t)(b * NCK + ck) * 2048 + d) * 16;
#pragma unroll
        for (int j = 0; j < 16; j += 4) {
            float4 hv = *(const float4*)(Hin + base + j);
            h[j] = hv.x; h[j + 1] = hv.y; h[j + 2] = hv.z; h[j + 3] = hv.w;
        }
    }
    const float Dv = Dp[d];
    __syncthreads();

    for (int l = 0; l < CL; ++l) {
        const size_t off = (size_t)(mb + l) * 2048 + d;
        const float dtv = dt[off];
        const float xv = bf2f(x_bf[off]);
        const float gv = gate[off];
        const float u = dtv * xv;
        float4 B0 = *(const float4*)&sBC[l][0];
        float4 B1 = *(const float4*)&sBC[l][4];
        float4 B2 = *(const float4*)&sBC[l][8];
        float4 B3 = *(const float4*)&sBC[l][12];
        float Bv[16] = {B0.x, B0.y, B0.z, B0.w, B1.x, B1.y, B1.z, B1.w,
                        B2.x, B2.y, B2.z, B2.w, B3.x, B3.y, B3.z, B3.w};
#pragma unroll
        for (int n = 0; n < 16; ++n) {
            const float dA = __builtin_amdgcn_exp2f(dtv * An2[n]);
            h[n] = fmaf(dA, h[n], Bv[n] * u);
        }
        float4 C0 = *(const float4*)&sBC[l][16];
        float4 C1 = *(const float4*)&sBC[l][20];
        float4 C2 = *(const float4*)&sBC[l][24];
        float4 C3 = *(const float4*)&sBC[l][28];
        float Cv[16] = {C0.x, C0.y, C0.z, C0.w, C1.x, C1.y, C1.z, C1.w,
                        C2.x, C2.y, C2.z, C2.w, C3.x, C3.y, C3.z, C3.w};
        float p = 0.f;
#pragma unroll
        for (int n = 0; n < 16; ++n)
            p = fmaf(h[n], Cv[n], p);
        y_bf[off] = f2bf(fmaf(xv, Dv, p) * siluf(gv));
    }
}

extern "C" void kernel_launch(void* const* d_in, const int* in_sizes, int n_in,
                              void* d_out, int out_size, void* d_ws, size_t ws_size,
                              hipStream_t stream)
{
    const float* hs     = (const float*)d_in[0];
    const float* W_in   = (const float*)d_in[1];
    const float* conv_w = (const float*)d_in[2];
    const float* conv_b = (const float*)d_in[3];
    const float* W_x    = (const float*)d_in[4];
    const float* W_dt   = (const float*)d_in[5];
    const float* b_dt   = (const float*)d_in[6];
    const float* A_log  = (const float*)d_in[7];
    const float* Dp     = (const float*)d_in[8];
    const float* W_out  = (const float*)d_in[9];
    float* out = (float*)d_out;

    // workspace (~74 MB live) with overlays
    float* ws    = (float*)d_ws;
    float* gate  = ws;                               // [2048 m][2048 d] f32
    float* dtb   = gate + (size_t)4194304;           // [2048 m][2048 d] f32
    float* projx = dtb + (size_t)4194304;            // [2048 d][2048 m] f32 (dead after conv)
    float* ssm_p = projx + (size_t)4194304;          // [2048 m][96] f32
    unsigned short* hs_bf    = (unsigned short*)(ssm_p + 196608);   // 2048*1024
    unsigned short* W_in_bf  = hs_bf + (size_t)2097152;             // 4096*1024
    unsigned short* W_out_bf = W_in_bf + (size_t)4194304;           // 1024*2048
    unsigned short* W_x_bf   = W_out_bf + (size_t)2097152;          // 96*2048
    unsigned short* W_dt_bf  = W_x_bf + (size_t)196608;             // 2048*64
    unsigned short* sp64_bf  = W_dt_bf + (size_t)131072;            // 2048*64
    unsigned short* x_bf     = sp64_bf + (size_t)131072;            // [2048 m][2048 d]
    float* P1   = projx;                              // overlay: ssm partials 16*2048*96
    float* Pch  = projx;                              // overlay after reduce_ssm: 2*32*2048*16
    float* Hch  = projx + (size_t)2097152;            // overlay
    float* Pout = gate;                               // overlay after scan_p2: 4*2048*1024
    unsigned short* y_bf = hs_bf;                     // overlay (hs_bf+W_in_bf dead)

    const int M = B_ * L_;  // 2048

    // 0. fused fp32 -> bf16 converts (hs, W_in, W_out, W_x, W_dt)
    cvt_all<<<(Q4 + 255) / 256, 256, 0, stream>>>(
        hs, W_in, W_out, W_x, W_dt, hs_bf, W_in_bf, W_out_bf, W_x_bf, W_dt_bf);

    // 1. proj GEMM, hybrid epilogue: x-half -> projx[d][m]; gate-half -> gate[m][d]
    gemm_bf16_nt<4><<<dim3(4096 / 128, M / 128, 1), 256, 0, stream>>>(
        hs_bf, W_in_bf, projx, 1024, 4096, 2048, 1024, 4096, 0, gate);

    // 2. conv + SiLU -> x_bf[m][d]
    conv_silu_kernel<<<dim3(D_ / 64, L_ / 64, B_), 256, 0, stream>>>(
        projx, conv_w, conv_b, x_bf);

    // 3. ssm partials: P1[z][m][96] = x @ W_x^T (K-chunk 128, 16 splits, plain stores)
    gemm_bf16_nt<0><<<dim3(1, M / 128, 16), 256, 0, stream>>>(
        x_bf, W_x_bf, P1, 2048, 96, 96, 128, 96, (size_t)2048 * 96, nullptr);

    // 3b. reduce partials -> ssm_p[m][96] + sp64_bf[m][64]
    reduce_ssm<<<(2048 * 24) / 256, 256, 0, stream>>>(P1, ssm_p, sp64_bf);

    // 4. dt[m][d] = softplus(dt_lr @ W_dt^T + b_dt[d]) — dedicated 64x64 kernel
    dt_gemm<<<dim3(2048 / 64, 2048 / 64), 256, 0, stream>>>(
        sp64_bf, W_dt_bf, dtb, b_dt);

    // 5. scan: pass1 -> combine -> pass2 (writes y_bf[m][d])
    scan_p1<<<dim3(D_ / 256, NCK, B_), 256, 0, stream>>>(
        dtb, x_bf, ssm_p, A_log, Pch, Hch);
    scan_combine<<<(B_ * D_ * 16) / 256, 256, 0, stream>>>(Pch, Hch);
    scan_p2<<<dim3(D_ / 256, NCK, B_), 256, 0, stream>>>(
        dtb, x_bf, gate, ssm_p, A_log, Dp, Pch, y_bf);

    // 6. out partials: Pout[z][m][1024] = y @ W_out^T (K-chunk 512, 4 splits)
    gemm_bf16_nt<0><<<dim3(1024 / 128, M / 128, 4), 256, 0, stream>>>(
        y_bf, W_out_bf, Pout, 2048, 1024, 1024, 512, 1024, (size_t)2048 * 1024, nullptr);

    // 6b. reduce 4 partials -> out
    reduce_out<<<(2048 * 1024 / 4) / 256, 256, 0, stream>>>(Pout, out);
}